// Round 13
// baseline (276.644 us; speedup 1.0000x reference)
//
#include <hip/hip_runtime.h>
#include <cstdint>
#include <cstddef>

// B=2, S=512, D_MODEL=512, H=8, dk=64, N_SAMPLES=16; R = B*H*S = 8192 rows.
// JAX partitionable threefry: bits[i] = o0^o1, (o0,o1)=threefry2x32((0,42),(0,i))
// u = (float)(bits>>9) * 2^-23 ; select iff u < p ⟺ bits < (ceil(p*2^23))<<9

#define ROTL(x, r) __builtin_rotateleft32((x), (r))

// 8-wide interleaved threefry rounds (arrays w/ constant indices -> registers).
#define QR8(s)                                                                \
  x0[0]+=x1[0];x0[1]+=x1[1];x0[2]+=x1[2];x0[3]+=x1[3];                        \
  x0[4]+=x1[4];x0[5]+=x1[5];x0[6]+=x1[6];x0[7]+=x1[7];                        \
  x1[0]=ROTL(x1[0],s);x1[1]=ROTL(x1[1],s);x1[2]=ROTL(x1[2],s);                \
  x1[3]=ROTL(x1[3],s);x1[4]=ROTL(x1[4],s);x1[5]=ROTL(x1[5],s);                \
  x1[6]=ROTL(x1[6],s);x1[7]=ROTL(x1[7],s);                                    \
  x1[0]^=x0[0];x1[1]^=x0[1];x1[2]^=x0[2];x1[3]^=x0[3];                        \
  x1[4]^=x0[4];x1[5]^=x0[5];x1[6]^=x0[6];x1[7]^=x0[7];
#define INJ8(X, Y)                                                            \
  x0[0]+=(X);x0[1]+=(X);x0[2]+=(X);x0[3]+=(X);                                \
  x0[4]+=(X);x0[5]+=(X);x0[6]+=(X);x0[7]+=(X);                                \
  x1[0]+=(Y);x1[1]+=(Y);x1[2]+=(Y);x1[3]+=(Y);                                \
  x1[4]+=(Y);x1[5]+=(Y);x1[6]+=(Y);x1[7]+=(Y);
#define INJ8Y(Y)                                                              \
  x1[0]+=(Y);x1[1]+=(Y);x1[2]+=(Y);x1[3]+=(Y);                                \
  x1[4]+=(Y);x1[5]+=(Y);x1[6]+=(Y);x1[7]+=(Y);

// ---------------------------------------------------------------------------
// Kernel A: QKV projection + out-init + fused V@Wo. grid=(16,8,4), block=256.
// z==0: Q GEMM;  z==1: K GEMM stored transposed KT[bh][d][k] (scatter);
// z==2: V GEMM -> registers -> LDS, then VW[bh][k][c] = Vtile @ Wo[h64:,:]
//       (this block holds the COMPLETE d-range of head h, so no dependency);
// z==3: out[b,s,:] = bo  (fused epilogue atomicAdds into it).
// Q/K values bit-exact vs prior rounds.
// ---------------------------------------------------------------------------
__global__ __launch_bounds__(256)
void qkv_gemm(const float* __restrict__ x,
              const float* __restrict__ Wq, const float* __restrict__ bq,
              const float* __restrict__ Wk, const float* __restrict__ bk,
              const float* __restrict__ Wv, const float* __restrict__ bv,
              const float* __restrict__ Wo, const float* __restrict__ bo,
              float* __restrict__ outp, float* __restrict__ Qw,
              float* __restrict__ KTw, float* __restrict__ VW) {
  const int tid = threadIdx.x;
  if (blockIdx.z == 3) {
    const int blk = blockIdx.y * 16 + blockIdx.x;        // 0..127
    const size_t base4 = (size_t)blk * 1024 + tid;       // float4 index
    const float4* bo4 = (const float4*)bo;
    float4* out4 = (float4*)outp;
#pragma unroll
    for (int i = 0; i < 4; ++i) {
      const size_t idx4 = base4 + (size_t)i * 256;
      out4[idx4] = bo4[idx4 & 127];
    }
    return;
  }
  const float* W; const float* bias;
  if (blockIdx.z == 0)      { W = Wq; bias = bq; }
  else if (blockIdx.z == 1) { W = Wk; bias = bk; }
  else                      { W = Wv; bias = bv; }

  __shared__ float At[32][68];
  __shared__ float Bs[32][64];
  __shared__ __align__(16) float Vt[64][68];   // z==2 V-tile
  __shared__ __align__(16) float Ws[64][33];   // z==2 Wo chunk
  const int tx = tid & 15, ty = tid >> 4;
  const int row0 = blockIdx.x * 64, col0 = blockIdx.y * 64;
  float acc[4][4] = {};

  for (int kk = 0; kk < 512; kk += 32) {
    const int ar = tid >> 2;
#pragma unroll
    for (int i = 0; i < 2; ++i) {
      const int kc = ((tid & 3) << 3) + (i << 2);
      const float4 a4 =
          *(const float4*)&x[(size_t)(row0 + ar) * 512 + kk + kc];
      At[kc + 0][ar] = a4.x; At[kc + 1][ar] = a4.y;
      At[kc + 2][ar] = a4.z; At[kc + 3][ar] = a4.w;
    }
#pragma unroll
    for (int i = 0; i < 2; ++i) {
      const int idx = tid + (i << 8);
      const int br = idx >> 4, bc = (idx & 15) << 2;
      *(float4*)&Bs[br][bc] =
          *(const float4*)&W[(size_t)(kk + br) * 512 + col0 + bc];
    }
    __syncthreads();
#pragma unroll
    for (int p = 0; p < 32; ++p) {
      const float4 a4 = *(const float4*)&At[p][ty << 2];
      const float4 b4 = *(const float4*)&Bs[p][tx << 2];
      acc[0][0] = fmaf(a4.x, b4.x, acc[0][0]); acc[0][1] = fmaf(a4.x, b4.y, acc[0][1]);
      acc[0][2] = fmaf(a4.x, b4.z, acc[0][2]); acc[0][3] = fmaf(a4.x, b4.w, acc[0][3]);
      acc[1][0] = fmaf(a4.y, b4.x, acc[1][0]); acc[1][1] = fmaf(a4.y, b4.y, acc[1][1]);
      acc[1][2] = fmaf(a4.y, b4.z, acc[1][2]); acc[1][3] = fmaf(a4.y, b4.w, acc[1][3]);
      acc[2][0] = fmaf(a4.z, b4.x, acc[2][0]); acc[2][1] = fmaf(a4.z, b4.y, acc[2][1]);
      acc[2][2] = fmaf(a4.z, b4.z, acc[2][2]); acc[2][3] = fmaf(a4.z, b4.w, acc[2][3]);
      acc[3][0] = fmaf(a4.w, b4.x, acc[3][0]); acc[3][1] = fmaf(a4.w, b4.y, acc[3][1]);
      acc[3][2] = fmaf(a4.w, b4.z, acc[3][2]); acc[3][3] = fmaf(a4.w, b4.w, acc[3][3]);
    }
    __syncthreads();
  }

  if (blockIdx.z == 0) {
#pragma unroll
    for (int i = 0; i < 4; ++i) {
      const int row = row0 + (ty << 2) + i;
      const int b = row >> 9, s = row & 511;
#pragma unroll
      for (int j = 0; j < 4; ++j) {
        const int col = col0 + (tx << 2) + j;
        const int h = col >> 6, d = col & 63;
        Qw[(((size_t)(b * 8 + h) * 512 + s) * 64) + d] =
            acc[i][j] + bias[col];
      }
    }
  } else if (blockIdx.z == 1) {
#pragma unroll
    for (int i = 0; i < 4; ++i) {
      const int row = row0 + (ty << 2) + i;
      const int b = row >> 9, s = row & 511;
#pragma unroll
      for (int j = 0; j < 4; ++j) {
        const int col = col0 + (tx << 2) + j;
        const int h = col >> 6, d = col & 63;
        KTw[(((size_t)(b * 8 + h) * 64 + d) * 512) + s] = acc[i][j] + bias[col];
      }
    }
  } else {
    // z==2: V tile (rows = (b,s), cols = head h's full d-range since
    // col0 = h*64). Second GEMM: VW[bh][s][c] += Vt @ Wo[h*64:(h+1)*64][:].
    const int h = blockIdx.y;
    const int b = row0 >> 9, s0 = row0 & 511;
    const int bh = b * 8 + h;
#pragma unroll
    for (int i = 0; i < 4; ++i) {
#pragma unroll
      for (int j = 0; j < 4; ++j) {
        Vt[(ty << 2) + i][(tx << 2) + j] =
            acc[i][j] + bias[col0 + (tx << 2) + j];
      }
    }
    const int tx2 = tid & 7, ty2 = tid >> 3;     // 8 c-groups x 32 row-groups
    for (int cc = 0; cc < 512; cc += 32) {
#pragma unroll
      for (int i = 0; i < 2; ++i) {              // stage Wo[64][32] chunk
        const int slot = tid + (i << 8);         // 0..511 float4 slots
        const int dr = slot >> 3, c4 = (slot & 7) << 2;
        *(float4*)&Ws[dr][c4] =
            *(const float4*)&Wo[(size_t)(h * 64 + dr) * 512 + cc + c4];
      }
      __syncthreads();
      float a2[2][4] = {};
#pragma unroll
      for (int p = 0; p < 64; ++p) {
        const float v0 = Vt[(ty2 << 1) + 0][p];
        const float v1 = Vt[(ty2 << 1) + 1][p];
        const float4 w4 = *(const float4*)&Ws[p][tx2 << 2];
        a2[0][0] = fmaf(v0, w4.x, a2[0][0]); a2[0][1] = fmaf(v0, w4.y, a2[0][1]);
        a2[0][2] = fmaf(v0, w4.z, a2[0][2]); a2[0][3] = fmaf(v0, w4.w, a2[0][3]);
        a2[1][0] = fmaf(v1, w4.x, a2[1][0]); a2[1][1] = fmaf(v1, w4.y, a2[1][1]);
        a2[1][2] = fmaf(v1, w4.z, a2[1][2]); a2[1][3] = fmaf(v1, w4.w, a2[1][3]);
      }
#pragma unroll
      for (int i = 0; i < 2; ++i) {
        float4 st; st.x = a2[i][0]; st.y = a2[i][1];
        st.z = a2[i][2]; st.w = a2[i][3];
        *(float4*)&VW[((size_t)(bh * 512 + s0 + (ty2 << 1) + i)) * 512 + cc +
                      (tx2 << 2)] = st;
      }
      __syncthreads();
    }
  }
}

// ---------------------------------------------------------------------------
// Kernel B (FUSED): scores + softmax + sampling + sparse out-accumulate.
// One block per row r (8192). Scores read KT coalesced; all fp orders for
// tf identical to passing rounds -> identical sampling bits.
// Tail: out[b,q,:] += sum_{k in nnz} wa_norm[k] * VW[bh][k][:]  (atomicAdd;
// out pre-initialized to bo by the qkv launch).
// ---------------------------------------------------------------------------
__global__ __launch_bounds__(256)
void fused_sample(const float* __restrict__ Q, const float* __restrict__ KT,
                  const float* __restrict__ VW, float* __restrict__ outp) {
  const int r = blockIdx.x;                   // 0..8191
  const int bh = r >> 9, q = r & 511;
  const int b = r >> 12;
  const int tid = threadIdx.x;
  __shared__ __align__(16) float qs[64];
  __shared__ float red[8];
  __shared__ float tf[512];
  __shared__ __align__(16) uint32_t pscu2[512];  // swizzled thresholds
  __shared__ float wa[512];
  __shared__ float wr[16];
  __shared__ float redc[8];
  __shared__ int   list[512];
  __shared__ int   cnt;

  if (tid == 0) cnt = 0;
  if (tid < 64) qs[tid] = Q[((size_t)bh * 512 + q) * 64 + tid];
  __syncthreads();

  // ---- scores: k = tid, tid+256, KT-coalesced (same fmaf order) ----
  float sc[2];
#pragma unroll
  for (int ii = 0; ii < 2; ++ii) {
    const int k = tid + (ii << 8);
    const float* Kp = KT + (size_t)bh * 64 * 512 + k;   // [d][k], stride 512
    float s = 0.f;
#pragma unroll
    for (int d4 = 0; d4 < 16; ++d4) {
      const float4 qv = ((const float4*)qs)[d4];
      const float k0 = Kp[(size_t)(d4 * 4 + 0) * 512];
      const float k1 = Kp[(size_t)(d4 * 4 + 1) * 512];
      const float k2 = Kp[(size_t)(d4 * 4 + 2) * 512];
      const float k3 = Kp[(size_t)(d4 * 4 + 3) * 512];
      s = fmaf(qv.x, k0, s); s = fmaf(qv.y, k1, s);
      s = fmaf(qv.z, k2, s); s = fmaf(qv.w, k3, s);
    }
    sc[ii] = s * 0.125f;
  }
  // ---- softmax (orders identical to split version) ----
  float mx = fmaxf(sc[0], sc[1]);
  for (int m = 1; m < 64; m <<= 1) mx = fmaxf(mx, __shfl_xor(mx, m));
  if ((tid & 63) == 0) red[tid >> 6] = mx;
  __syncthreads();
  const float rowmax = fmaxf(fmaxf(red[0], red[1]), fmaxf(red[2], red[3]));
  const float e0 = expf(sc[0] - rowmax);
  const float e1 = expf(sc[1] - rowmax);
  float ssum = e0 + e1;
  for (int m = 1; m < 64; m <<= 1) ssum += __shfl_xor(ssum, m);
  if ((tid & 63) == 0) red[4 + (tid >> 6)] = ssum;
  __syncthreads();
  const float tot = red[4] + red[5] + red[6] + red[7];
  const float t0 = e0 / tot, t1 = e1 / tot;
  tf[tid] = t0; tf[tid + 256] = t1;
  wa[tid] = 0.f; wa[tid + 256] = 0.f;
  {
    const float p0 = fmaf(0.5f, t0, 0.0009765625f);
    const float p1 = fmaf(0.5f, t1, 0.0009765625f);
    // swizzle: k -> ((k&31)>>2)*64 + (k>>5)*4 + (k&3)
    {
      const int k = tid;
      pscu2[(((k & 31) >> 2) << 6) + ((k >> 5) << 2) + (k & 3)] =
          ((uint32_t)ceilf(p0 * 8388608.0f)) << 9;
    }
    {
      const int k = tid + 256;
      pscu2[(((k & 31) >> 2) << 6) + ((k >> 5) << 2) + (k & 3)] =
          ((uint32_t)ceilf(p1 * 8388608.0f)) << 9;
    }
    float ql = (1.f - p0) * (1.f - p1);       // Qrow partial
    for (int m = 1; m < 64; m <<= 1) ql *= __shfl_xor(ql, m);
    if ((tid & 63) == 0) redc[4 + (tid >> 6)] = ql;
  }
  __syncthreads();
  const float Qrow = redc[4] * redc[5] * redc[6] * redc[7];

  // ---- sampling: lane t covers contiguous k = t*32+j ----
  const int n = tid >> 4, t = tid & 15;
  const int k0i = t << 5;
  const uint32_t cbase =
      (uint32_t)r * 8192u + (uint32_t)n * 512u + (uint32_t)k0i + 42u;
  uint32_t bits = 0u;
#pragma unroll
  for (int jb = 0; jb < 32; jb += 8) {
    uint32_t x0[8], x1[8];
#pragma unroll
    for (int i = 0; i < 8; ++i) {
      const uint32_t c = cbase + (uint32_t)(jb + i);
      x0[i] = c;                        // round-1 fold: x0 was 0
      x1[i] = ROTL(c, 13) ^ c;
    }
    QR8(15) QR8(26) QR8(6)
    INJ8(42u, 0x1BD11BF1u)
    QR8(17) QR8(29) QR8(16) QR8(24)
    INJ8(0x1BD11BF0u, 2u)
    QR8(13) QR8(15) QR8(26) QR8(6)
    INJ8Y(45u)
    QR8(17) QR8(29) QR8(16) QR8(24)
    INJ8(42u, 0x1BD11BF4u)
    QR8(13) QR8(15) QR8(26) QR8(6)
    INJ8(0x1BD11BF0u, 5u)
    const uint4 pA = *(const uint4*)&pscu2[((jb >> 2) << 6) + (t << 2)];
    const uint4 pB = *(const uint4*)&pscu2[(((jb >> 2) + 1) << 6) + (t << 2)];
    bits |= (uint32_t)((x0[0] ^ x1[0]) < pA.x) << (jb + 0);
    bits |= (uint32_t)((x0[1] ^ x1[1]) < pA.y) << (jb + 1);
    bits |= (uint32_t)((x0[2] ^ x1[2]) < pA.z) << (jb + 2);
    bits |= (uint32_t)((x0[3] ^ x1[3]) < pA.w) << (jb + 3);
    bits |= (uint32_t)((x0[4] ^ x1[4]) < pB.x) << (jb + 4);
    bits |= (uint32_t)((x0[5] ^ x1[5]) < pB.y) << (jb + 5);
    bits |= (uint32_t)((x0[6] ^ x1[6]) < pB.z) << (jb + 6);
    bits |= (uint32_t)((x0[7] ^ x1[7]) < pB.w) << (jb + 7);
  }

  // rare path: selected-term products (expected ~1 selection per sample)
  float ptl = 1.f, ratl = 1.f;
  int cl = __popc(bits);
  {
    uint32_t bb = bits;
    while (bb) {
      const int j = __builtin_ctz(bb);
      bb &= bb - 1u;
      const float tv = tf[k0i + j];
      const float p = fmaf(0.5f, tv, 0.0009765625f);
      ptl *= tv;
      ratl *= p / (1.f - p);
    }
  }
#pragma unroll
  for (int m = 1; m < 16; m <<= 1) {
    ptl *= __shfl_xor(ptl, m);
    ratl *= __shfl_xor(ratl, m);
    cl += __shfl_xor(cl, m);
  }
  if (t == 0) {
    const float pp = Qrow * ratl;
    wr[n] = (cl > 0 && pp > 0.f) ? (ptl / fmaxf(pp, 1e-38f)) : 0.f;
  }
  __syncthreads();
  float wsum = 0.f;
#pragma unroll
  for (int m2 = 0; m2 < 16; ++m2) wsum += wr[m2];
  const float wn = (wsum > 0.f) ? (wr[n] / fmaxf(wsum, 1e-38f)) : 0.0625f;
  {
    uint32_t bb = bits;
    while (bb) {
      const int j = __builtin_ctz(bb);
      bb &= bb - 1u;
      atomicAdd(&wa[k0i + j], wn);
    }
  }
  __syncthreads();

  // row sum + compact nonzeros
  float sp = wa[tid] + wa[tid + 256];
  for (int m = 1; m < 64; m <<= 1) sp += __shfl_xor(sp, m);
  if ((tid & 63) == 0) redc[tid >> 6] = sp;
  if (wa[tid] > 0.f)       { const int i = atomicAdd(&cnt, 1); list[i] = tid; }
  if (wa[tid + 256] > 0.f) { const int i = atomicAdd(&cnt, 1); list[i] = tid + 256; }
  __syncthreads();
  const float was = redc[0] + redc[1] + redc[2] + redc[3];
  const int nnz = cnt;

  // ---- sparse out-accumulate: out += sum_k wa_norm[k] * VW[bh][k][:] ----
  const float* VWb = VW + ((size_t)bh * 512) * 512;
  float a0 = 0.f, a1 = 0.f;
  if (was > 0.f) {
    const float inv = 1.f / fmaxf(was, 1e-38f);
    for (int i = 0; i < nnz; ++i) {
      const int k = list[i];
      const float w = wa[k] * inv;
      a0 = fmaf(w, VWb[(size_t)k * 512 + tid], a0);
      a1 = fmaf(w, VWb[(size_t)k * 512 + tid + 256], a1);
    }
  } else {
    for (int k = 0; k < 512; ++k) {
      a0 += VWb[(size_t)k * 512 + tid];
      a1 += VWb[(size_t)k * 512 + tid + 256];
    }
    a0 *= 0.001953125f; a1 *= 0.001953125f;
  }
  float* orow = outp + ((size_t)(b * 512 + q)) * 512;
  atomicAdd(&orow[tid], a0);
  atomicAdd(&orow[tid + 256], a1);
}

// ---------------------------------------------------------------------------
extern "C" void kernel_launch(void* const* d_in, const int* in_sizes, int n_in,
                              void* d_out, int out_size, void* d_ws,
                              size_t ws_size, hipStream_t stream) {
  const float* x  = (const float*)d_in[0];
  const float* Wq = (const float*)d_in[1];
  const float* bq = (const float*)d_in[2];
  const float* Wk = (const float*)d_in[3];
  const float* bk = (const float*)d_in[4];
  const float* Wv = (const float*)d_in[5];
  const float* bv = (const float*)d_in[6];
  const float* Wo = (const float*)d_in[7];
  const float* bo = (const float*)d_in[8];
  float* out = (float*)d_out;

  float* ws = (float*)d_ws;
  float* Qw = ws;                  // 524288 f32  [B,H,S,dk]
  float* KT = ws + 524288;         // 524288     [B,H,dk,S]
  float* VW = ws + 1048576;        // 4194304    [B,H,S,512]  (V @ Wo_h)

  dim3 gq(16, 8, 4);
  qkv_gemm<<<gq, 256, 0, stream>>>(x, Wq, bq, Wk, bk, Wv, bv, Wo, bo, out,
                                   Qw, KT, VW);
  fused_sample<<<8192, 256, 0, stream>>>(Qw, KT, VW, out);
}

// Round 14
// 274.729 us; speedup vs baseline: 1.0070x; 1.0070x over previous
//
#include <hip/hip_runtime.h>
#include <cstdint>
#include <cstddef>

// B=2, S=512, D_MODEL=512, H=8, dk=64, N_SAMPLES=16; R = B*H*S = 8192 rows.
// JAX partitionable threefry: bits[i] = o0^o1, (o0,o1)=threefry2x32((0,42),(0,i))
// u = (float)(bits>>9) * 2^-23 ; select iff u < p ⟺ bits < (ceil(p*2^23))<<9

#define ROTL(x, r) __builtin_rotateleft32((x), (r))

#define QR8(s)                                                                \
  x0[0]+=x1[0];x0[1]+=x1[1];x0[2]+=x1[2];x0[3]+=x1[3];                        \
  x0[4]+=x1[4];x0[5]+=x1[5];x0[6]+=x1[6];x0[7]+=x1[7];                        \
  x1[0]=ROTL(x1[0],s);x1[1]=ROTL(x1[1],s);x1[2]=ROTL(x1[2],s);                \
  x1[3]=ROTL(x1[3],s);x1[4]=ROTL(x1[4],s);x1[5]=ROTL(x1[5],s);                \
  x1[6]=ROTL(x1[6],s);x1[7]=ROTL(x1[7],s);                                    \
  x1[0]^=x0[0];x1[1]^=x0[1];x1[2]^=x0[2];x1[3]^=x0[3];                        \
  x1[4]^=x0[4];x1[5]^=x0[5];x1[6]^=x0[6];x1[7]^=x0[7];
#define INJ8(X, Y)                                                            \
  x0[0]+=(X);x0[1]+=(X);x0[2]+=(X);x0[3]+=(X);                                \
  x0[4]+=(X);x0[5]+=(X);x0[6]+=(X);x0[7]+=(X);                                \
  x1[0]+=(Y);x1[1]+=(Y);x1[2]+=(Y);x1[3]+=(Y);                                \
  x1[4]+=(Y);x1[5]+=(Y);x1[6]+=(Y);x1[7]+=(Y);
#define INJ8Y(Y)                                                              \
  x1[0]+=(Y);x1[1]+=(Y);x1[2]+=(Y);x1[3]+=(Y);                                \
  x1[4]+=(Y);x1[5]+=(Y);x1[6]+=(Y);x1[7]+=(Y);

// ---------------------------------------------------------------------------
// Kernel A: QKV projection + out-init + fused V@Wo. grid=(32,8,4), block=256.
// 32x64 tiles (1024 blocks -> co-resident, straggler-free balance).
// z==0: Q GEMM;  z==1: K GEMM stored transposed KT[bh][d][k];
// z==2: V GEMM -> LDS -> VW[bh][k][c] = Vtile @ Wo[h*64:(h+1)*64, :];
// z==3: out[b,s,:] = bo.   Per-element k-order unchanged -> bit-exact Q/K/V.
// ---------------------------------------------------------------------------
__global__ __launch_bounds__(256)
void qkv_gemm(const float* __restrict__ x,
              const float* __restrict__ Wq, const float* __restrict__ bq,
              const float* __restrict__ Wk, const float* __restrict__ bk,
              const float* __restrict__ Wv, const float* __restrict__ bv,
              const float* __restrict__ Wo, const float* __restrict__ bo,
              float* __restrict__ outp, float* __restrict__ Qw,
              float* __restrict__ KTw, float* __restrict__ VW) {
  const int tid = threadIdx.x;
  if (blockIdx.z == 3) {
    const int blk = blockIdx.y * 32 + blockIdx.x;        // 0..255
    const size_t base4 = (size_t)blk * 512 + tid;        // float4 index
    const float4* bo4 = (const float4*)bo;
    float4* out4 = (float4*)outp;
#pragma unroll
    for (int i = 0; i < 2; ++i) {
      const size_t idx4 = base4 + (size_t)i * 256;
      out4[idx4] = bo4[idx4 & 127];
    }
    return;
  }
  const float* W; const float* bias;
  if (blockIdx.z == 0)      { W = Wq; bias = bq; }
  else if (blockIdx.z == 1) { W = Wk; bias = bk; }
  else                      { W = Wv; bias = bv; }

  __shared__ float At[32][34];   // [k][m]
  __shared__ float Bs[32][64];   // [k][n]
  __shared__ float Vt[32][65];   // z==2 V-tile (stride 65: conflict-free cols)
  __shared__ __align__(16) float Ws[64][36];   // z==2 Wo chunk (36: f4-aligned)
  const int tx = tid & 15, ty = tid >> 4;
  const int row0 = blockIdx.x * 32, col0 = blockIdx.y * 64;
  float acc[2][4] = {};

  for (int kk = 0; kk < 512; kk += 32) {
    {
      const int rr = tid >> 3, cc = (tid & 7) << 2;      // A: 1 float4
      const float4 a4 = *(const float4*)&x[(size_t)(row0 + rr) * 512 + kk + cc];
      At[cc + 0][rr] = a4.x; At[cc + 1][rr] = a4.y;
      At[cc + 2][rr] = a4.z; At[cc + 3][rr] = a4.w;
#pragma unroll
      for (int i = 0; i < 2; ++i) {                      // B: 2 float4
        const int idx = tid + (i << 8);
        const int br = idx >> 4, bc = (idx & 15) << 2;
        *(float4*)&Bs[br][bc] =
            *(const float4*)&W[(size_t)(kk + br) * 512 + col0 + bc];
      }
    }
    __syncthreads();
#pragma unroll
    for (int p = 0; p < 32; ++p) {
      const float2 a2 = *(const float2*)&At[p][ty * 2];
      const float4 b4 = *(const float4*)&Bs[p][tx * 4];
      acc[0][0] = fmaf(a2.x, b4.x, acc[0][0]); acc[0][1] = fmaf(a2.x, b4.y, acc[0][1]);
      acc[0][2] = fmaf(a2.x, b4.z, acc[0][2]); acc[0][3] = fmaf(a2.x, b4.w, acc[0][3]);
      acc[1][0] = fmaf(a2.y, b4.x, acc[1][0]); acc[1][1] = fmaf(a2.y, b4.y, acc[1][1]);
      acc[1][2] = fmaf(a2.y, b4.z, acc[1][2]); acc[1][3] = fmaf(a2.y, b4.w, acc[1][3]);
    }
    __syncthreads();
  }

  if (blockIdx.z == 0) {
#pragma unroll
    for (int i = 0; i < 2; ++i) {
      const int row = row0 + ty * 2 + i;
      const int b = row >> 9, s = row & 511;
#pragma unroll
      for (int j = 0; j < 4; ++j) {
        const int col = col0 + tx * 4 + j;
        const int h = col >> 6, d = col & 63;
        Qw[(((size_t)(b * 8 + h) * 512 + s) * 64) + d] = acc[i][j] + bias[col];
      }
    }
  } else if (blockIdx.z == 1) {
#pragma unroll
    for (int i = 0; i < 2; ++i) {
      const int row = row0 + ty * 2 + i;
      const int b = row >> 9, s = row & 511;
#pragma unroll
      for (int j = 0; j < 4; ++j) {
        const int col = col0 + tx * 4 + j;
        const int h = col >> 6, d = col & 63;
        KTw[(((size_t)(b * 8 + h) * 64 + d) * 512) + s] = acc[i][j] + bias[col];
      }
    }
  } else {
    // z==2: V tile rows=(b,s) 32 of them, cols = head h's full d-range.
    const int h = blockIdx.y;
    const int b = row0 >> 9, s0 = row0 & 511;
    const int bh = b * 8 + h;
#pragma unroll
    for (int i = 0; i < 2; ++i) {
#pragma unroll
      for (int j = 0; j < 4; ++j) {
        Vt[ty * 2 + i][tx * 4 + j] = acc[i][j] + bias[col0 + tx * 4 + j];
      }
    }
    // VW[bh][s0+row][c] = sum_d Vt[row][d] * Wo[h*64+d][c]
    const int tx2 = tid & 7, ty2 = tid >> 3;   // 8 col-groups x 32 rows
    for (int cc = 0; cc < 512; cc += 32) {
#pragma unroll
      for (int i = 0; i < 2; ++i) {            // stage Wo[64][32] chunk
        const int slot = tid + (i << 8);       // 0..511 float4 slots
        const int dr = slot >> 3, c4 = (slot & 7) << 2;
        *(float4*)&Ws[dr][c4] =
            *(const float4*)&Wo[(size_t)(h * 64 + dr) * 512 + cc + c4];
      }
      __syncthreads();
      float a2[4] = {};
#pragma unroll
      for (int p = 0; p < 64; ++p) {
        const float v0 = Vt[ty2][p];
        const float4 w4 = *(const float4*)&Ws[p][tx2 << 2];
        a2[0] = fmaf(v0, w4.x, a2[0]); a2[1] = fmaf(v0, w4.y, a2[1]);
        a2[2] = fmaf(v0, w4.z, a2[2]); a2[3] = fmaf(v0, w4.w, a2[3]);
      }
      float4 st; st.x = a2[0]; st.y = a2[1]; st.z = a2[2]; st.w = a2[3];
      *(float4*)&VW[((size_t)(bh * 512 + s0 + ty2)) * 512 + cc + (tx2 << 2)] =
          st;
      __syncthreads();
    }
  }
}

// ---------------------------------------------------------------------------
// Kernel B (FUSED): scores + softmax + sampling + sparse out-accumulate.
// One block per row; r XCD-swizzled so each XCD works on 2 bh panels (VW
// panel set ~4MB = fits per-XCD L2). All fp orders identical to passing
// rounds -> identical sampling bits.
// ---------------------------------------------------------------------------
__global__ __launch_bounds__(256)
void fused_sample(const float* __restrict__ Q, const float* __restrict__ KT,
                  const float* __restrict__ VW, float* __restrict__ outp) {
  // XCD-aware remap: consecutive blockIdx round-robin across 8 XCDs; give
  // XCD j the contiguous r-range [j*1024, (j+1)*1024) -> 2 bh panels/XCD.
  const int r = ((blockIdx.x & 7) << 10) + (blockIdx.x >> 3);   // 0..8191
  const int bh = r >> 9, q = r & 511;
  const int b = r >> 12;
  const int tid = threadIdx.x;
  __shared__ __align__(16) float qs[64];
  __shared__ float red[8];
  __shared__ float tf[512];
  __shared__ __align__(16) uint32_t pscu2[512];  // swizzled thresholds
  __shared__ float wa[512];
  __shared__ float wr[16];
  __shared__ float redc[8];
  __shared__ int   list[512];
  __shared__ int   cnt;

  if (tid == 0) cnt = 0;
  if (tid < 64) qs[tid] = Q[((size_t)bh * 512 + q) * 64 + tid];
  __syncthreads();

  // ---- scores: k = tid, tid+256, KT-coalesced (same fmaf order) ----
  float sc[2];
#pragma unroll
  for (int ii = 0; ii < 2; ++ii) {
    const int k = tid + (ii << 8);
    const float* Kp = KT + (size_t)bh * 64 * 512 + k;   // [d][k], stride 512
    float s = 0.f;
#pragma unroll
    for (int d4 = 0; d4 < 16; ++d4) {
      const float4 qv = ((const float4*)qs)[d4];
      const float k0 = Kp[(size_t)(d4 * 4 + 0) * 512];
      const float k1 = Kp[(size_t)(d4 * 4 + 1) * 512];
      const float k2 = Kp[(size_t)(d4 * 4 + 2) * 512];
      const float k3 = Kp[(size_t)(d4 * 4 + 3) * 512];
      s = fmaf(qv.x, k0, s); s = fmaf(qv.y, k1, s);
      s = fmaf(qv.z, k2, s); s = fmaf(qv.w, k3, s);
    }
    sc[ii] = s * 0.125f;
  }
  // ---- softmax ----
  float mx = fmaxf(sc[0], sc[1]);
  for (int m = 1; m < 64; m <<= 1) mx = fmaxf(mx, __shfl_xor(mx, m));
  if ((tid & 63) == 0) red[tid >> 6] = mx;
  __syncthreads();
  const float rowmax = fmaxf(fmaxf(red[0], red[1]), fmaxf(red[2], red[3]));
  const float e0 = expf(sc[0] - rowmax);
  const float e1 = expf(sc[1] - rowmax);
  float ssum = e0 + e1;
  for (int m = 1; m < 64; m <<= 1) ssum += __shfl_xor(ssum, m);
  if ((tid & 63) == 0) red[4 + (tid >> 6)] = ssum;
  __syncthreads();
  const float tot = red[4] + red[5] + red[6] + red[7];
  const float t0 = e0 / tot, t1 = e1 / tot;
  tf[tid] = t0; tf[tid + 256] = t1;
  wa[tid] = 0.f; wa[tid + 256] = 0.f;
  {
    const float p0 = fmaf(0.5f, t0, 0.0009765625f);
    const float p1 = fmaf(0.5f, t1, 0.0009765625f);
    {
      const int k = tid;
      pscu2[(((k & 31) >> 2) << 6) + ((k >> 5) << 2) + (k & 3)] =
          ((uint32_t)ceilf(p0 * 8388608.0f)) << 9;
    }
    {
      const int k = tid + 256;
      pscu2[(((k & 31) >> 2) << 6) + ((k >> 5) << 2) + (k & 3)] =
          ((uint32_t)ceilf(p1 * 8388608.0f)) << 9;
    }
    float ql = (1.f - p0) * (1.f - p1);       // Qrow partial
    for (int m = 1; m < 64; m <<= 1) ql *= __shfl_xor(ql, m);
    if ((tid & 63) == 0) redc[4 + (tid >> 6)] = ql;
  }
  __syncthreads();
  const float Qrow = redc[4] * redc[5] * redc[6] * redc[7];

  // ---- sampling: lane t covers contiguous k = t*32+j ----
  const int n = tid >> 4, t = tid & 15;
  const int k0i = t << 5;
  const uint32_t cbase =
      (uint32_t)r * 8192u + (uint32_t)n * 512u + (uint32_t)k0i + 42u;
  uint32_t bits = 0u;
#pragma unroll
  for (int jb = 0; jb < 32; jb += 8) {
    uint32_t x0[8], x1[8];
#pragma unroll
    for (int i = 0; i < 8; ++i) {
      const uint32_t c = cbase + (uint32_t)(jb + i);
      x0[i] = c;                        // round-1 fold: x0 was 0
      x1[i] = ROTL(c, 13) ^ c;
    }
    QR8(15) QR8(26) QR8(6)
    INJ8(42u, 0x1BD11BF1u)
    QR8(17) QR8(29) QR8(16) QR8(24)
    INJ8(0x1BD11BF0u, 2u)
    QR8(13) QR8(15) QR8(26) QR8(6)
    INJ8Y(45u)
    QR8(17) QR8(29) QR8(16) QR8(24)
    INJ8(42u, 0x1BD11BF4u)
    QR8(13) QR8(15) QR8(26) QR8(6)
    INJ8(0x1BD11BF0u, 5u)
    const uint4 pA = *(const uint4*)&pscu2[((jb >> 2) << 6) + (t << 2)];
    const uint4 pB = *(const uint4*)&pscu2[(((jb >> 2) + 1) << 6) + (t << 2)];
    bits |= (uint32_t)((x0[0] ^ x1[0]) < pA.x) << (jb + 0);
    bits |= (uint32_t)((x0[1] ^ x1[1]) < pA.y) << (jb + 1);
    bits |= (uint32_t)((x0[2] ^ x1[2]) < pA.z) << (jb + 2);
    bits |= (uint32_t)((x0[3] ^ x1[3]) < pA.w) << (jb + 3);
    bits |= (uint32_t)((x0[4] ^ x1[4]) < pB.x) << (jb + 4);
    bits |= (uint32_t)((x0[5] ^ x1[5]) < pB.y) << (jb + 5);
    bits |= (uint32_t)((x0[6] ^ x1[6]) < pB.z) << (jb + 6);
    bits |= (uint32_t)((x0[7] ^ x1[7]) < pB.w) << (jb + 7);
  }

  // rare path: selected-term products
  float ptl = 1.f, ratl = 1.f;
  int cl = __popc(bits);
  {
    uint32_t bb = bits;
    while (bb) {
      const int j = __builtin_ctz(bb);
      bb &= bb - 1u;
      const float tv = tf[k0i + j];
      const float p = fmaf(0.5f, tv, 0.0009765625f);
      ptl *= tv;
      ratl *= p / (1.f - p);
    }
  }
#pragma unroll
  for (int m = 1; m < 16; m <<= 1) {
    ptl *= __shfl_xor(ptl, m);
    ratl *= __shfl_xor(ratl, m);
    cl += __shfl_xor(cl, m);
  }
  if (t == 0) {
    const float pp = Qrow * ratl;
    wr[n] = (cl > 0 && pp > 0.f) ? (ptl / fmaxf(pp, 1e-38f)) : 0.f;
  }
  __syncthreads();
  float wsum = 0.f;
#pragma unroll
  for (int m2 = 0; m2 < 16; ++m2) wsum += wr[m2];
  const float wn = (wsum > 0.f) ? (wr[n] / fmaxf(wsum, 1e-38f)) : 0.0625f;
  {
    uint32_t bb = bits;
    while (bb) {
      const int j = __builtin_ctz(bb);
      bb &= bb - 1u;
      atomicAdd(&wa[k0i + j], wn);
    }
  }
  __syncthreads();

  // row sum + compact nonzeros
  float sp = wa[tid] + wa[tid + 256];
  for (int m = 1; m < 64; m <<= 1) sp += __shfl_xor(sp, m);
  if ((tid & 63) == 0) redc[tid >> 6] = sp;
  if (wa[tid] > 0.f)       { const int i = atomicAdd(&cnt, 1); list[i] = tid; }
  if (wa[tid + 256] > 0.f) { const int i = atomicAdd(&cnt, 1); list[i] = tid + 256; }
  __syncthreads();
  const float was = redc[0] + redc[1] + redc[2] + redc[3];
  const int nnz = cnt;

  // ---- sparse out-accumulate: out += sum_k wa_norm[k] * VW[bh][k][:] ----
  const float* VWb = VW + ((size_t)bh * 512) * 512;
  float a0 = 0.f, a1 = 0.f;
  if (was > 0.f) {
    const float inv = 1.f / fmaxf(was, 1e-38f);
    for (int i = 0; i < nnz; ++i) {
      const int k = list[i];
      const float w = wa[k] * inv;
      a0 = fmaf(w, VWb[(size_t)k * 512 + tid], a0);
      a1 = fmaf(w, VWb[(size_t)k * 512 + tid + 256], a1);
    }
  } else {
    for (int k = 0; k < 512; ++k) {
      a0 += VWb[(size_t)k * 512 + tid];
      a1 += VWb[(size_t)k * 512 + tid + 256];
    }
    a0 *= 0.001953125f; a1 *= 0.001953125f;
  }
  float* orow = outp + ((size_t)(b * 512 + q)) * 512;
  atomicAdd(&orow[tid], a0);
  atomicAdd(&orow[tid + 256], a1);
}

// ---------------------------------------------------------------------------
extern "C" void kernel_launch(void* const* d_in, const int* in_sizes, int n_in,
                              void* d_out, int out_size, void* d_ws,
                              size_t ws_size, hipStream_t stream) {
  const float* x  = (const float*)d_in[0];
  const float* Wq = (const float*)d_in[1];
  const float* bq = (const float*)d_in[2];
  const float* Wk = (const float*)d_in[3];
  const float* bk = (const float*)d_in[4];
  const float* Wv = (const float*)d_in[5];
  const float* bv = (const float*)d_in[6];
  const float* Wo = (const float*)d_in[7];
  const float* bo = (const float*)d_in[8];
  float* out = (float*)d_out;

  float* ws = (float*)d_ws;
  float* Qw = ws;                  // 524288 f32  [B,H,S,dk]
  float* KT = ws + 524288;         // 524288     [B,H,dk,S]
  float* VW = ws + 1048576;        // 4194304    [B,H,S,512]  (V @ Wo_h)

  dim3 gq(32, 8, 4);
  qkv_gemm<<<gq, 256, 0, stream>>>(x, Wq, bq, Wk, bk, Wv, bv, Wo, bo, out,
                                   Qw, KT, VW);
  fused_sample<<<8192, 256, 0, stream>>>(Qw, KT, VW, out);
}

// Round 15
// 250.227 us; speedup vs baseline: 1.1056x; 1.0979x over previous
//
#include <hip/hip_runtime.h>
#include <cstdint>
#include <cstddef>

// B=2, S=512, D_MODEL=512, H=8, dk=64, N_SAMPLES=16; R = B*H*S = 8192 rows.
// JAX partitionable threefry: bits[i] = o0^o1, (o0,o1)=threefry2x32((0,42),(0,i))
// u = (float)(bits>>9) * 2^-23 ; select iff u < p ⟺ bits < (ceil(p*2^23))<<9

#define ROTL(x, r) __builtin_rotateleft32((x), (r))

#define QR8(s)                                                                \
  x0[0]+=x1[0];x0[1]+=x1[1];x0[2]+=x1[2];x0[3]+=x1[3];                        \
  x0[4]+=x1[4];x0[5]+=x1[5];x0[6]+=x1[6];x0[7]+=x1[7];                        \
  x1[0]=ROTL(x1[0],s);x1[1]=ROTL(x1[1],s);x1[2]=ROTL(x1[2],s);                \
  x1[3]=ROTL(x1[3],s);x1[4]=ROTL(x1[4],s);x1[5]=ROTL(x1[5],s);                \
  x1[6]=ROTL(x1[6],s);x1[7]=ROTL(x1[7],s);                                    \
  x1[0]^=x0[0];x1[1]^=x0[1];x1[2]^=x0[2];x1[3]^=x0[3];                        \
  x1[4]^=x0[4];x1[5]^=x0[5];x1[6]^=x0[6];x1[7]^=x0[7];
#define INJ8(X, Y)                                                            \
  x0[0]+=(X);x0[1]+=(X);x0[2]+=(X);x0[3]+=(X);                                \
  x0[4]+=(X);x0[5]+=(X);x0[6]+=(X);x0[7]+=(X);                                \
  x1[0]+=(Y);x1[1]+=(Y);x1[2]+=(Y);x1[3]+=(Y);                                \
  x1[4]+=(Y);x1[5]+=(Y);x1[6]+=(Y);x1[7]+=(Y);
#define INJ8Y(Y)                                                              \
  x1[0]+=(Y);x1[1]+=(Y);x1[2]+=(Y);x1[3]+=(Y);                                \
  x1[4]+=(Y);x1[5]+=(Y);x1[6]+=(Y);x1[7]+=(Y);

// ---------------------------------------------------------------------------
// Kernel A: QKV projection + out-init. grid=(16,8,4), block=256. 64x64 tiles.
// z==0: Q GEMM -> Qw[bh][s][d];
// z==1: K GEMM -> LDS transpose (union w/ At,Bs) -> KT[bh][d][k] float4 store;
// z==2: V GEMM -> Vw[bh][s][d];
// z==3: out[b,s,:] = bo  (fused epilogue atomicAdds into it).
// All values bit-exact vs R11 (same k-order; only K's store path changed).
// ---------------------------------------------------------------------------
__global__ __launch_bounds__(256)
void qkv_gemm(const float* __restrict__ x,
              const float* __restrict__ Wq, const float* __restrict__ bq,
              const float* __restrict__ Wk, const float* __restrict__ bk,
              const float* __restrict__ Wv, const float* __restrict__ bv,
              const float* __restrict__ bo, float* __restrict__ outp,
              float* __restrict__ Qw, float* __restrict__ KTw,
              float* __restrict__ Vw) {
  const int tid = threadIdx.x;
  if (blockIdx.z == 3) {
    const int blk = blockIdx.y * 16 + blockIdx.x;        // 0..127
    const size_t base4 = (size_t)blk * 1024 + tid;       // float4 index
    const float4* bo4 = (const float4*)bo;
    float4* out4 = (float4*)outp;
#pragma unroll
    for (int i = 0; i < 4; ++i) {
      const size_t idx4 = base4 + (size_t)i * 256;
      out4[idx4] = bo4[idx4 & 127];
    }
    return;
  }
  const float* W; const float* bias;
  if (blockIdx.z == 0)      { W = Wq; bias = bq; }
  else if (blockIdx.z == 1) { W = Wk; bias = bk; }
  else                      { W = Wv; bias = bv; }

  // Union: At[32][68] + Bs[32][64] (main loop)  |  T2[64][68] (K epilogue)
  __shared__ __align__(16) float smem[64 * 68];
  float (*At)[68] = (float(*)[68])smem;                 // 32 rows used
  float (*Bs)[64] = (float(*)[64])(smem + 32 * 68);     // 32x64
  float (*T2)[68] = (float(*)[68])smem;                 // 64x68 (K transpose)

  const int tx = tid & 15, ty = tid >> 4;
  const int row0 = blockIdx.x * 64, col0 = blockIdx.y * 64;
  float acc[4][4] = {};

  for (int kk = 0; kk < 512; kk += 32) {
    const int ar = tid >> 2;
#pragma unroll
    for (int i = 0; i < 2; ++i) {
      const int kc = ((tid & 3) << 3) + (i << 2);
      const float4 a4 =
          *(const float4*)&x[(size_t)(row0 + ar) * 512 + kk + kc];
      At[kc + 0][ar] = a4.x; At[kc + 1][ar] = a4.y;
      At[kc + 2][ar] = a4.z; At[kc + 3][ar] = a4.w;
    }
#pragma unroll
    for (int i = 0; i < 2; ++i) {
      const int idx = tid + (i << 8);
      const int br = idx >> 4, bc = (idx & 15) << 2;
      *(float4*)&Bs[br][bc] =
          *(const float4*)&W[(size_t)(kk + br) * 512 + col0 + bc];
    }
    __syncthreads();
#pragma unroll
    for (int p = 0; p < 32; ++p) {
      const float4 a4 = *(const float4*)&At[p][ty << 2];
      const float4 b4 = *(const float4*)&Bs[p][tx << 2];
      acc[0][0] = fmaf(a4.x, b4.x, acc[0][0]); acc[0][1] = fmaf(a4.x, b4.y, acc[0][1]);
      acc[0][2] = fmaf(a4.x, b4.z, acc[0][2]); acc[0][3] = fmaf(a4.x, b4.w, acc[0][3]);
      acc[1][0] = fmaf(a4.y, b4.x, acc[1][0]); acc[1][1] = fmaf(a4.y, b4.y, acc[1][1]);
      acc[1][2] = fmaf(a4.y, b4.z, acc[1][2]); acc[1][3] = fmaf(a4.y, b4.w, acc[1][3]);
      acc[2][0] = fmaf(a4.z, b4.x, acc[2][0]); acc[2][1] = fmaf(a4.z, b4.y, acc[2][1]);
      acc[2][2] = fmaf(a4.z, b4.z, acc[2][2]); acc[2][3] = fmaf(a4.z, b4.w, acc[2][3]);
      acc[3][0] = fmaf(a4.w, b4.x, acc[3][0]); acc[3][1] = fmaf(a4.w, b4.y, acc[3][1]);
      acc[3][2] = fmaf(a4.w, b4.z, acc[3][2]); acc[3][3] = fmaf(a4.w, b4.w, acc[3][3]);
    }
    __syncthreads();
  }

  if (blockIdx.z == 0) {
#pragma unroll
    for (int i = 0; i < 4; ++i) {
      const int row = row0 + (ty << 2) + i;
      const int b = row >> 9, s = row & 511;
#pragma unroll
      for (int j = 0; j < 4; ++j) {
        const int col = col0 + (tx << 2) + j;
        const int h = col >> 6, d = col & 63;
        Qw[(((size_t)(b * 8 + h) * 512 + s) * 64) + d] = acc[i][j] + bias[col];
      }
    }
  } else if (blockIdx.z == 1) {
    // K: transpose 64x64 tile through LDS (union buffer), float4 stores.
#pragma unroll
    for (int i = 0; i < 4; ++i) {
#pragma unroll
      for (int j = 0; j < 4; ++j) {
        const int col = col0 + (tx << 2) + j;
        T2[(tx << 2) + j][(ty << 2) + i] = acc[i][j] + bias[col];
      }
    }
    __syncthreads();
    const int c = tid >> 2, seg = tid & 3;     // c = d-index, seg = s-quarter
    const int b = row0 >> 9, h = blockIdx.y;
    const int s0 = (row0 & 511) + (seg << 4);
    float* dst = KTw + (((size_t)(b * 8 + h) * 64 + c) << 9) + s0;
#pragma unroll
    for (int i2 = 0; i2 < 4; ++i2) {
      *(float4*)&dst[i2 << 2] = *(const float4*)&T2[c][(seg << 4) + (i2 << 2)];
    }
  } else {
#pragma unroll
    for (int i = 0; i < 4; ++i) {
      const int row = row0 + (ty << 2) + i;
      const int b = row >> 9, s = row & 511;
#pragma unroll
      for (int j = 0; j < 4; ++j) {
        const int col = col0 + (tx << 2) + j;
        const int h = col >> 6, d = col & 63;
        Vw[(((size_t)(b * 8 + h) * 512 + s) * 64) + d] = acc[i][j] + bias[col];
      }
    }
  }
}

// ---------------------------------------------------------------------------
// Kernel B (FUSED): scores + softmax + sampling + sparse attn@V + out-proj.
// One block per row; r XCD-swizzled (each XCD -> 2 contiguous bh panels, so
// KT/V panels stay L2-resident). All fp orders identical to R11 -> identical
// tf bits, Bernoulli bits, and output arithmetic.
// ---------------------------------------------------------------------------
__global__ __launch_bounds__(256)
void fused_sample(const float* __restrict__ Q, const float* __restrict__ KT,
                  const float* __restrict__ V, const float* __restrict__ Wo,
                  float* __restrict__ outp) {
  const int r = ((blockIdx.x & 7) << 10) + (blockIdx.x >> 3);   // 0..8191
  const int bh = r >> 9, q = r & 511;
  const int b = r >> 12, h = (r >> 9) & 7;
  const int tid = threadIdx.x;
  __shared__ __align__(16) float qs[64];
  __shared__ float red[8];
  __shared__ float tf[512];
  __shared__ __align__(16) uint32_t pscu2[512];  // swizzled thresholds
  __shared__ float wa[512];
  __shared__ float wr[16];
  __shared__ float redc[8];
  __shared__ float psum[4][64];
  __shared__ float o_s[64];
  __shared__ int   list[512];
  __shared__ int   cnt;

  if (tid == 0) cnt = 0;
  if (tid < 64) qs[tid] = Q[((size_t)bh * 512 + q) * 64 + tid];
  __syncthreads();

  // ---- scores: k = tid, tid+256, KT-coalesced (same fmaf order) ----
  float sc[2];
#pragma unroll
  for (int ii = 0; ii < 2; ++ii) {
    const int k = tid + (ii << 8);
    const float* Kp = KT + (size_t)bh * 64 * 512 + k;   // [d][k], stride 512
    float s = 0.f;
#pragma unroll
    for (int d4 = 0; d4 < 16; ++d4) {
      const float4 qv = ((const float4*)qs)[d4];
      const float k0 = Kp[(size_t)(d4 * 4 + 0) * 512];
      const float k1 = Kp[(size_t)(d4 * 4 + 1) * 512];
      const float k2 = Kp[(size_t)(d4 * 4 + 2) * 512];
      const float k3 = Kp[(size_t)(d4 * 4 + 3) * 512];
      s = fmaf(qv.x, k0, s); s = fmaf(qv.y, k1, s);
      s = fmaf(qv.z, k2, s); s = fmaf(qv.w, k3, s);
    }
    sc[ii] = s * 0.125f;
  }
  // ---- softmax ----
  float mx = fmaxf(sc[0], sc[1]);
  for (int m = 1; m < 64; m <<= 1) mx = fmaxf(mx, __shfl_xor(mx, m));
  if ((tid & 63) == 0) red[tid >> 6] = mx;
  __syncthreads();
  const float rowmax = fmaxf(fmaxf(red[0], red[1]), fmaxf(red[2], red[3]));
  const float e0 = expf(sc[0] - rowmax);
  const float e1 = expf(sc[1] - rowmax);
  float ssum = e0 + e1;
  for (int m = 1; m < 64; m <<= 1) ssum += __shfl_xor(ssum, m);
  if ((tid & 63) == 0) red[4 + (tid >> 6)] = ssum;
  __syncthreads();
  const float tot = red[4] + red[5] + red[6] + red[7];
  const float t0 = e0 / tot, t1 = e1 / tot;
  tf[tid] = t0; tf[tid + 256] = t1;
  wa[tid] = 0.f; wa[tid + 256] = 0.f;
  {
    const float p0 = fmaf(0.5f, t0, 0.0009765625f);
    const float p1 = fmaf(0.5f, t1, 0.0009765625f);
    // swizzle: k -> ((k&31)>>2)*64 + (k>>5)*4 + (k&3)
    {
      const int k = tid;
      pscu2[(((k & 31) >> 2) << 6) + ((k >> 5) << 2) + (k & 3)] =
          ((uint32_t)ceilf(p0 * 8388608.0f)) << 9;
    }
    {
      const int k = tid + 256;
      pscu2[(((k & 31) >> 2) << 6) + ((k >> 5) << 2) + (k & 3)] =
          ((uint32_t)ceilf(p1 * 8388608.0f)) << 9;
    }
    float ql = (1.f - p0) * (1.f - p1);       // Qrow partial
    for (int m = 1; m < 64; m <<= 1) ql *= __shfl_xor(ql, m);
    if ((tid & 63) == 0) redc[4 + (tid >> 6)] = ql;
  }
  __syncthreads();
  const float Qrow = redc[4] * redc[5] * redc[6] * redc[7];

  // ---- sampling: lane t covers contiguous k = t*32+j ----
  const int n = tid >> 4, t = tid & 15;
  const int k0i = t << 5;
  const uint32_t cbase =
      (uint32_t)r * 8192u + (uint32_t)n * 512u + (uint32_t)k0i + 42u;
  uint32_t bits = 0u;
#pragma unroll
  for (int jb = 0; jb < 32; jb += 8) {
    uint32_t x0[8], x1[8];
#pragma unroll
    for (int i = 0; i < 8; ++i) {
      const uint32_t c = cbase + (uint32_t)(jb + i);
      x0[i] = c;                        // round-1 fold: x0 was 0
      x1[i] = ROTL(c, 13) ^ c;
    }
    QR8(15) QR8(26) QR8(6)
    INJ8(42u, 0x1BD11BF1u)
    QR8(17) QR8(29) QR8(16) QR8(24)
    INJ8(0x1BD11BF0u, 2u)
    QR8(13) QR8(15) QR8(26) QR8(6)
    INJ8Y(45u)
    QR8(17) QR8(29) QR8(16) QR8(24)
    INJ8(42u, 0x1BD11BF4u)
    QR8(13) QR8(15) QR8(26) QR8(6)
    INJ8(0x1BD11BF0u, 5u)
    const uint4 pA = *(const uint4*)&pscu2[((jb >> 2) << 6) + (t << 2)];
    const uint4 pB = *(const uint4*)&pscu2[(((jb >> 2) + 1) << 6) + (t << 2)];
    bits |= (uint32_t)((x0[0] ^ x1[0]) < pA.x) << (jb + 0);
    bits |= (uint32_t)((x0[1] ^ x1[1]) < pA.y) << (jb + 1);
    bits |= (uint32_t)((x0[2] ^ x1[2]) < pA.z) << (jb + 2);
    bits |= (uint32_t)((x0[3] ^ x1[3]) < pA.w) << (jb + 3);
    bits |= (uint32_t)((x0[4] ^ x1[4]) < pB.x) << (jb + 4);
    bits |= (uint32_t)((x0[5] ^ x1[5]) < pB.y) << (jb + 5);
    bits |= (uint32_t)((x0[6] ^ x1[6]) < pB.z) << (jb + 6);
    bits |= (uint32_t)((x0[7] ^ x1[7]) < pB.w) << (jb + 7);
  }

  // rare path: selected-term products (expected ~1 selection per sample)
  float ptl = 1.f, ratl = 1.f;
  int cl = __popc(bits);
  {
    uint32_t bb = bits;
    while (bb) {
      const int j = __builtin_ctz(bb);
      bb &= bb - 1u;
      const float tv = tf[k0i + j];
      const float p = fmaf(0.5f, tv, 0.0009765625f);
      ptl *= tv;
      ratl *= p / (1.f - p);
    }
  }
#pragma unroll
  for (int m = 1; m < 16; m <<= 1) {
    ptl *= __shfl_xor(ptl, m);
    ratl *= __shfl_xor(ratl, m);
    cl += __shfl_xor(cl, m);
  }
  if (t == 0) {
    const float pp = Qrow * ratl;
    wr[n] = (cl > 0 && pp > 0.f) ? (ptl / fmaxf(pp, 1e-38f)) : 0.f;
  }
  __syncthreads();
  float wsum = 0.f;
#pragma unroll
  for (int m2 = 0; m2 < 16; ++m2) wsum += wr[m2];
  const float wn = (wsum > 0.f) ? (wr[n] / fmaxf(wsum, 1e-38f)) : 0.0625f;
  {
    uint32_t bb = bits;
    while (bb) {
      const int j = __builtin_ctz(bb);
      bb &= bb - 1u;
      atomicAdd(&wa[k0i + j], wn);
    }
  }
  __syncthreads();

  // row sum + compact nonzeros
  float sp = wa[tid] + wa[tid + 256];
  for (int m = 1; m < 64; m <<= 1) sp += __shfl_xor(sp, m);
  if ((tid & 63) == 0) redc[tid >> 6] = sp;
  if (wa[tid] > 0.f)       { const int i = atomicAdd(&cnt, 1); list[i] = tid; }
  if (wa[tid + 256] > 0.f) { const int i = atomicAdd(&cnt, 1); list[i] = tid + 256; }
  __syncthreads();
  const float was = redc[0] + redc[1] + redc[2] + redc[3];
  const int nnz = cnt;

  // sparse attn @ V over ~16 nonzero k
  const int g = tid >> 6, d = tid & 63;
  const float* Vb = V + ((size_t)(b * 8 + h) * 512) * 64;
  float acc = 0.f;
  if (was > 0.f) {
    const float inv = 1.f / fmaxf(was, 1e-38f);
    for (int i = g; i < nnz; i += 4) {
      const int k = list[i];
      acc = fmaf(wa[k] * inv, Vb[(size_t)k * 64 + d], acc);
    }
  } else {
    for (int k = g; k < 512; k += 4) acc += Vb[(size_t)k * 64 + d];
    acc *= 0.001953125f;
  }
  psum[g][d] = acc;
  __syncthreads();
  if (g == 0)
    o_s[d] = psum[0][d] + psum[1][d] + psum[2][d] + psum[3][d];
  __syncthreads();

  // ---- fused out-projection: out[b,q,col] += sum_d o_s[d]*Wo[h*64+d,col]
  {
    const float* Wh = Wo + ((size_t)h * 64) * 512;
    float a0 = 0.f, a1 = 0.f;
#pragma unroll 8
    for (int dd = 0; dd < 64; ++dd) {
      const float ov = o_s[dd];
      a0 = fmaf(ov, Wh[(size_t)dd * 512 + tid], a0);
      a1 = fmaf(ov, Wh[(size_t)dd * 512 + tid + 256], a1);
    }
    float* orow = outp + ((size_t)(b * 512 + q)) * 512;
    atomicAdd(&orow[tid], a0);
    atomicAdd(&orow[tid + 256], a1);
  }
}

// ---------------------------------------------------------------------------
extern "C" void kernel_launch(void* const* d_in, const int* in_sizes, int n_in,
                              void* d_out, int out_size, void* d_ws,
                              size_t ws_size, hipStream_t stream) {
  const float* x  = (const float*)d_in[0];
  const float* Wq = (const float*)d_in[1];
  const float* bq = (const float*)d_in[2];
  const float* Wk = (const float*)d_in[3];
  const float* bk = (const float*)d_in[4];
  const float* Wv = (const float*)d_in[5];
  const float* bv = (const float*)d_in[6];
  const float* Wo = (const float*)d_in[7];
  const float* bo = (const float*)d_in[8];
  float* out = (float*)d_out;

  float* ws = (float*)d_ws;
  float* Qw = ws;                  // 524288 f32  [B,H,S,dk]
  float* KT = ws + 524288;         // 524288     [B,H,dk,S]
  float* Vw = ws + 1048576;        // 524288     [B,H,S,dk]

  dim3 gq(16, 8, 4);
  qkv_gemm<<<gq, 256, 0, stream>>>(x, Wq, bq, Wk, bk, Wv, bv, bo, out,
                                   Qw, KT, Vw);
  fused_sample<<<8192, 256, 0, stream>>>(Qw, KT, Vw, Wo, out);
}